// Round 10
// baseline (113.731 us; speedup 1.0000x reference)
//
#include <hip/hip_runtime.h>
#include <stdint.h>

// SSIM fused kernel v10, MI355X (gfx950).
// v9 post-mortem: padding did NOT move SQ_LDS_BANK_CONFLICT (1.6e7) -> my
// bank model of rbAB/sp/st strides was wrong. Differential evidence: v2/v4
// (direct-global stage-1, no staging) had 0 conflicts with the same rb
// patterns; v8 added staging and conflicts appeared -> conflicts attributed
// to the sp/st staging path. v10 removes staging:
//  - Stage 1 reads pred/targ directly from global (v4's 0-conflict structure:
//    interior float4 fast path, guarded scalar boundary path; halo re-reads
//    are L1/L2-served).
//  - Keeps v8's packed-f32 scatter math + RTN fp16 rbAB storage + f32 rbC.
//  - LDS 37.9 -> 20.0 KB -> 6 blocks/CU (__launch_bounds__(256,6), VGPR cap
//    84 > natural ~55). One less barrier.

#define HH 512
#define WW 512
#define PLANES 48
#define TW 64
#define TH 16
#define RR 5
#define KK 11
#define IN_H (TH + 2 * RR)        // 26
#define NBLOCKS (PLANES * (WW / TW) * (HH / TH))  // 12288
#define NTHREADS 256
#define NITEMS (IN_H * (TW / 4))  // 416
#define TOTAL_ELEMS (PLANES * HH * WW)

typedef _Float16 half2v __attribute__((ext_vector_type(2)));
typedef float float2v __attribute__((ext_vector_type(2)));

constexpr float G_[KK] = {
    1.4867195147342977e-06f, 1.3383022576488537e-04f, 4.4318484119380075e-03f,
    5.3990966513188063e-02f, 2.4197072451914337e-01f, 3.9894228040143270e-01f,
    2.4197072451914337e-01f, 5.3990966513188063e-02f, 4.4318484119380075e-03f,
    1.3383022576488537e-04f, 1.4867195147342977e-06f};

__device__ __forceinline__ half2v u2h(uint32_t u) {
  return __builtin_bit_cast(half2v, u);
}
// RTN fp16 pack — unbiased (v4/v8 verified; RTZ pack is NOT safe, v7).
__device__ __forceinline__ uint32_t packrtn(float a, float b) {
  half2v h = {(_Float16)a, (_Float16)b};
  return __builtin_bit_cast(uint32_t, h);
}

__global__ __launch_bounds__(NTHREADS, 6) void ssim_tile_kernel(
    const float* __restrict__ pred, const float* __restrict__ targ,
    float* __restrict__ partial) {
  __shared__ __align__(16) uint2 rbAB[IN_H][TW];  // 13.3 KB {pack(p,t),pack(pp,tt)}
  __shared__ __align__(16) float rbC[IN_H][TW];   // 6.7 KB conv_pt f32
  __shared__ float wsums[4];

  const int tid = threadIdx.x;
  const int bid = blockIdx.x;
  const int plane = bid >> 8;
  const int tile = bid & 255;
  const int x0 = (tile & 7) * TW;
  const int y0 = (tile >> 3) * TH;
  const float* pp = pred + (size_t)plane * (HH * WW);
  const float* tp = targ + (size_t)plane * (HH * WW);

  const bool interior = (x0 >= 64) && (x0 <= 384) && (y0 >= 16) && (y0 <= 480);

  // ---- Stage 1: row conv of 5 quantities, direct from global ----
  for (int i = tid; i < NITEMS; i += NTHREADS) {
    const int r = i >> 4;            // 0..25 halo row
    const int c4 = (i & 15) << 2;    // 0..60 output col group
    const int gy = y0 + r - RR;

    // window: global cols x0+c4-8 .. x0+c4+11 (20 floats, 16B-aligned start);
    // used positions: 3..16.
    float4 pf[5], tf[5];
    if (interior) {
      const float* prow = pp + gy * WW + (x0 + c4 - 8);
      const float* trow = tp + gy * WW + (x0 + c4 - 8);
#pragma unroll
      for (int u = 0; u < 5; ++u) {
        pf[u] = reinterpret_cast<const float4*>(prow)[u];
        tf[u] = reinterpret_cast<const float4*>(trow)[u];
      }
    } else {
      float pw[20], tw[20];
      if (gy >= 0 && gy < HH) {
        const float* prow = pp + gy * WW;
        const float* trow = tp + gy * WW;
#pragma unroll
        for (int j = 0; j < 20; ++j) {
          int gx = x0 + c4 - 8 + j;
          bool ok = (j >= 3) && (j <= 16) && (gx >= 0) && (gx < WW);
          pw[j] = ok ? prow[gx] : 0.f;
          tw[j] = ok ? trow[gx] : 0.f;
        }
      } else {
#pragma unroll
        for (int j = 0; j < 20; ++j) { pw[j] = 0.f; tw[j] = 0.f; }
      }
#pragma unroll
      for (int u = 0; u < 5; ++u) {
        pf[u] = make_float4(pw[4*u], pw[4*u+1], pw[4*u+2], pw[4*u+3]);
        tf[u] = make_float4(tw[4*u], tw[4*u+1], tw[4*u+2], tw[4*u+3]);
      }
    }

    // Scatter form, packed f32: position idx (3..16) contributes to outputs
    // j in [idx-13, idx-3] ∩ [0,3] with weight G_[idx-3-j].
    float2v s01[4] = {{0,0},{0,0},{0,0},{0,0}};
    float2v s23[4] = {{0,0},{0,0},{0,0},{0,0}};
    float s4[4] = {0,0,0,0};
#pragma unroll
    for (int u = 0; u < 5; ++u) {
#pragma unroll
      for (int e = 0; e < 4; ++e) {
        const int idx = 4 * u + e;
        if (idx < 3 || idx > 16) continue;
        const float a = reinterpret_cast<const float*>(&pf[u])[e];
        const float b = reinterpret_cast<const float*>(&tf[u])[e];
        const float2v av = {a, b};
        const float2v sq = av * av;    // v_pk_mul_f32
        const float ab = a * b;
#pragma unroll
        for (int j = 0; j < 4; ++j) {
          if (j < idx - 13 || j > idx - 3) continue;
          const float w = G_[idx - 3 - j];
          const float2v w2 = {w, w};
          s01[j] = __builtin_elementwise_fma(w2, av, s01[j]);  // v_pk_fma_f32
          s23[j] = __builtin_elementwise_fma(w2, sq, s23[j]);
          s4[j] = fmaf(w, ab, s4[j]);
        }
      }
    }

    uint4 w1, w2s;
    w1.x = packrtn(s01[0].x, s01[0].y); w1.y = packrtn(s23[0].x, s23[0].y);
    w1.z = packrtn(s01[1].x, s01[1].y); w1.w = packrtn(s23[1].x, s23[1].y);
    w2s.x = packrtn(s01[2].x, s01[2].y); w2s.y = packrtn(s23[2].x, s23[2].y);
    w2s.z = packrtn(s01[3].x, s01[3].y); w2s.w = packrtn(s23[3].x, s23[3].y);
    *reinterpret_cast<uint4*>(&rbAB[r][c4]) = w1;
    *reinterpret_cast<uint4*>(&rbAB[r][c4 + 2]) = w2s;
    *reinterpret_cast<float4*>(&rbC[r][c4]) =
        make_float4(s4[0], s4[1], s4[2], s4[3]);
  }
  __syncthreads();

  // ---- Stage 2: column conv (packed f32) + SSIM map ----
  float lsum = 0.f;
  {
    const int x = tid & 63;
    const int ybase = (tid >> 6) * 4;  // 0,4,8,12
    float2v fa[14], fb[14];
    float vc[14];
#pragma unroll
    for (int m = 0; m < 14; ++m) {
      uint2 q = rbAB[ybase + m][x];    // ds_read_b64
      half2v ha = u2h(q.x), hb = u2h(q.y);
      fa[m] = float2v{(float)ha.x, (float)ha.y};
      fb[m] = float2v{(float)hb.x, (float)hb.y};
      vc[m] = rbC[ybase + m][x];
    }

    float2v accA[4], accB[4];
    float sC[4];
#pragma unroll
    for (int j = 0; j < 4; ++j) {
      float2v a = {0, 0}, b = {0, 0};
      float c = 0.f;
#pragma unroll
      for (int k = 0; k < KK; ++k) {
        const float2v w2 = {G_[k], G_[k]};
        a = __builtin_elementwise_fma(w2, fa[j + k], a);
        b = __builtin_elementwise_fma(w2, fb[j + k], b);
        c = fmaf(G_[k], vc[j + k], c);
      }
      accA[j] = a; accB[j] = b; sC[j] = c;
    }

    const float C1 = 1.0e-4f;
    const float C2 = 9.0e-4f;
#pragma unroll
    for (int j = 0; j < 4; ++j) {
      float mu_x = accA[j].x;
      float mu_y = accA[j].y;
      float sxx = accB[j].x - mu_x * mu_x;
      float syy = accB[j].y - mu_y * mu_y;
      float sxy = sC[j] - mu_x * mu_y;
      float num = (2.f * mu_x * mu_y + C1) * (2.f * sxy + C2);
      float den = (mu_x * mu_x + mu_y * mu_y + C1) *
                  (sxx * sxx + syy * syy + C2);
      lsum = fmaf(num, __builtin_amdgcn_rcpf(den), lsum);
    }
  }

  // ---- Block reduction -> partial[bid] ----
#pragma unroll
  for (int off = 32; off > 0; off >>= 1) lsum += __shfl_xor(lsum, off, 64);
  if ((tid & 63) == 0) wsums[tid >> 6] = lsum;
  __syncthreads();
  if (tid == 0)
    partial[bid] = (wsums[0] + wsums[1]) + (wsums[2] + wsums[3]);
}

__global__ __launch_bounds__(1024) void ssim_reduce_kernel(
    const float* __restrict__ partial, float* __restrict__ out) {
  float s = 0.f;
  for (int i = threadIdx.x; i < NBLOCKS; i += 1024) s += partial[i];
#pragma unroll
  for (int off = 32; off > 0; off >>= 1) s += __shfl_xor(s, off, 64);
  __shared__ float ws[16];
  if ((threadIdx.x & 63) == 0) ws[threadIdx.x >> 6] = s;
  __syncthreads();
  if (threadIdx.x == 0) {
    float t = 0.f;
#pragma unroll
    for (int i = 0; i < 16; ++i) t += ws[i];
    out[0] = t * (1.0f / (float)TOTAL_ELEMS);
  }
}

extern "C" void kernel_launch(void* const* d_in, const int* in_sizes, int n_in,
                              void* d_out, int out_size, void* d_ws,
                              size_t ws_size, hipStream_t stream) {
  const float* pred = (const float*)d_in[0];
  const float* targ = (const float*)d_in[1];
  float* out = (float*)d_out;
  float* partial = (float*)d_ws;

  ssim_tile_kernel<<<NBLOCKS, NTHREADS, 0, stream>>>(pred, targ, partial);
  ssim_reduce_kernel<<<1, 1024, 0, stream>>>(partial, out);
}

// Round 11
// 83.311 us; speedup vs baseline: 1.3651x; 1.3651x over previous
//
#include <hip/hip_runtime.h>
#include <stdint.h>

// SSIM fused kernel v11, MI355X (gfx950).
// v10 post-mortem: removing LDS staging killed the conflicts (1.6e7->1.3e6)
// but cost 26 us: direct-global stage-1 reintroduces ~200cy VMEM latency
// chains; VALUBusy fell 64->51. Staging stays. Occupancy plateaus at ~39%
// for 4 AND 6 blocks/CU (v4/v8/v10) -> occupancy plays dead.
// v11 = v8 base with stage-1 restructured to 8-col items:
//  - 208 items (26 rows x 8 groups), ONE per thread, single shot: stage-1
//    critical path 2 items -> 1 item; window loads 12 b128 per 8 outputs
//    (vs 10 per 4); products/packs/addr amortized 2x.
//  - SW=84 (8-row bank-phase spread for the 8-rows-per-wave read pattern).
//  - __launch_bounds__(256,4): VGPR cap 128 > natural ~110, no spills.
//  - Stage-2: + pk_fma(-A,A,B) for sxx/syy; otherwise unchanged from v8.

#define HH 512
#define WW 512
#define PLANES 48
#define TW 64
#define TH 16
#define RR 5
#define KK 11
#define IN_H (TH + 2 * RR)        // 26
#define SW 84                      // sp/st row stride (80 staged cols used)
#define NBLOCKS (PLANES * (WW / TW) * (HH / TH))  // 12288
#define NTHREADS 256
#define NSTAGE (IN_H * 20)        // 520 staging granules
#define NITEMS (IN_H * 8)         // 208 row-conv items (row, 8-col group)
#define TOTAL_ELEMS (PLANES * HH * WW)

typedef _Float16 half2v __attribute__((ext_vector_type(2)));
typedef float float2v __attribute__((ext_vector_type(2)));

constexpr float G_[KK] = {
    1.4867195147342977e-06f, 1.3383022576488537e-04f, 4.4318484119380075e-03f,
    5.3990966513188063e-02f, 2.4197072451914337e-01f, 3.9894228040143270e-01f,
    2.4197072451914337e-01f, 5.3990966513188063e-02f, 4.4318484119380075e-03f,
    1.3383022576488537e-04f, 1.4867195147342977e-06f};

__device__ __forceinline__ half2v u2h(uint32_t u) {
  return __builtin_bit_cast(half2v, u);
}
// RTN fp16 pack — unbiased (v4/v8 verified; RTZ pack is NOT safe, v7).
__device__ __forceinline__ uint32_t packrtn(float a, float b) {
  half2v h = {(_Float16)a, (_Float16)b};
  return __builtin_bit_cast(uint32_t, h);
}

__global__ __launch_bounds__(NTHREADS, 4) void ssim_tile_kernel(
    const float* __restrict__ pred, const float* __restrict__ targ,
    float* __restrict__ partial) {
  __shared__ __align__(16) float sp[IN_H][SW];    // 8.7 KB raw pred
  __shared__ __align__(16) float st[IN_H][SW];    // 8.7 KB raw targ
  __shared__ __align__(16) uint2 rbAB[IN_H][TW];  // 13.3 KB {pk(p,t),pk(pp,tt)}
  __shared__ __align__(16) float rbC[IN_H][TW];   // 6.7 KB conv_pt f32
  __shared__ float wsums[4];

  const int tid = threadIdx.x;
  const int bid = blockIdx.x;
  const int plane = bid >> 8;
  const int tile = bid & 255;
  const int x0 = (tile & 7) * TW;
  const int y0 = (tile >> 3) * TH;
  const float* pp = pred + (size_t)plane * (HH * WW);
  const float* tp = targ + (size_t)plane * (HH * WW);

  // ---- Stage 0: stage raw halo (granule-aligned float4, uniform path) ----
  for (int i = tid; i < NSTAGE; i += NTHREADS) {
    const int r = i / 20;            // halo row 0..25
    const int cg = i - r * 20;       // granule 0..19
    const int gy = y0 + r - RR;
    const int gx = x0 - 8 + cg * 4;  // granule start, 16B aligned
    float4 pv = make_float4(0.f, 0.f, 0.f, 0.f);
    float4 tv = pv;
    if (gy >= 0 && gy < HH && gx >= 0 && gx <= WW - 4) {
      const int o = gy * WW + gx;
      pv = *reinterpret_cast<const float4*>(pp + o);
      tv = *reinterpret_cast<const float4*>(tp + o);
    }
    *reinterpret_cast<float4*>(&sp[r][cg * 4]) = pv;
    *reinterpret_cast<float4*>(&st[r][cg * 4]) = tv;
  }
  __syncthreads();

  // ---- Stage 1: row conv of 5 quantities, 8 outputs/thread, one shot ----
  if (tid < NITEMS) {
    const int r = tid >> 3;          // 0..25
    const int c8 = (tid & 7) << 3;   // 0..56 output col group base
    // staged window cols c8 .. c8+23 (global x0+c8-8 .. x0+c8+15)
    float pw[24], tw[24];
#pragma unroll
    for (int u = 0; u < 6; ++u) {
      float4 a = *reinterpret_cast<const float4*>(&sp[r][c8 + 4 * u]);
      float4 b = *reinterpret_cast<const float4*>(&st[r][c8 + 4 * u]);
      pw[4*u+0] = a.x; pw[4*u+1] = a.y; pw[4*u+2] = a.z; pw[4*u+3] = a.w;
      tw[4*u+0] = b.x; tw[4*u+1] = b.y; tw[4*u+2] = b.z; tw[4*u+3] = b.w;
    }

    // Scatter form, packed f32. Window position q (3..20) contributes to
    // outputs j in [q-13, q-3] ∩ [0,7] with weight G_[q-3-j].
    float2v s01[8] = {{0,0},{0,0},{0,0},{0,0},{0,0},{0,0},{0,0},{0,0}};
    float2v s23[8] = {{0,0},{0,0},{0,0},{0,0},{0,0},{0,0},{0,0},{0,0}};
    float s4[8] = {0,0,0,0,0,0,0,0};
#pragma unroll
    for (int q = 3; q <= 20; ++q) {
      const float a = pw[q];
      const float b = tw[q];
      const float2v av = {a, b};
      const float2v sq = av * av;      // v_pk_mul_f32
      const float ab = a * b;
#pragma unroll
      for (int j = 0; j < 8; ++j) {
        if (j < q - 13 || j > q - 3) continue;
        const float w = G_[q - 3 - j];
        const float2v w2 = {w, w};
        s01[j] = __builtin_elementwise_fma(w2, av, s01[j]);  // v_pk_fma_f32
        s23[j] = __builtin_elementwise_fma(w2, sq, s23[j]);
        s4[j] = fmaf(w, ab, s4[j]);
      }
    }

#pragma unroll
    for (int h = 0; h < 4; ++h) {    // 4 x uint4 = cols c8..c8+7
      uint4 wv;
      wv.x = packrtn(s01[2*h].x,   s01[2*h].y);
      wv.y = packrtn(s23[2*h].x,   s23[2*h].y);
      wv.z = packrtn(s01[2*h+1].x, s01[2*h+1].y);
      wv.w = packrtn(s23[2*h+1].x, s23[2*h+1].y);
      *reinterpret_cast<uint4*>(&rbAB[r][c8 + 2*h]) = wv;
    }
    *reinterpret_cast<float4*>(&rbC[r][c8]) =
        make_float4(s4[0], s4[1], s4[2], s4[3]);
    *reinterpret_cast<float4*>(&rbC[r][c8 + 4]) =
        make_float4(s4[4], s4[5], s4[6], s4[7]);
  }
  __syncthreads();

  // ---- Stage 2: column conv (packed f32) + SSIM map ----
  float lsum = 0.f;
  {
    const int x = tid & 63;
    const int ybase = (tid >> 6) * 4;  // 0,4,8,12
    float2v fa[14], fb[14];
    float vc[14];
#pragma unroll
    for (int m = 0; m < 14; ++m) {
      uint2 q = rbAB[ybase + m][x];    // ds_read_b64
      half2v ha = u2h(q.x), hb = u2h(q.y);
      fa[m] = float2v{(float)ha.x, (float)ha.y};
      fb[m] = float2v{(float)hb.x, (float)hb.y};
      vc[m] = rbC[ybase + m][x];
    }

    float2v accA[4], accB[4];
    float sC[4];
#pragma unroll
    for (int j = 0; j < 4; ++j) {
      float2v a = {0, 0}, b = {0, 0};
      float c = 0.f;
#pragma unroll
      for (int k = 0; k < KK; ++k) {
        const float2v w2 = {G_[k], G_[k]};
        a = __builtin_elementwise_fma(w2, fa[j + k], a);
        b = __builtin_elementwise_fma(w2, fb[j + k], b);
        c = fmaf(G_[k], vc[j + k], c);
      }
      accA[j] = a; accB[j] = b; sC[j] = c;
    }

    const float C1 = 1.0e-4f;
    const float C2 = 9.0e-4f;
#pragma unroll
    for (int j = 0; j < 4; ++j) {
      const float mu_x = accA[j].x;
      const float mu_y = accA[j].y;
      // {sxx, syy} = accB - accA*accA in one pk_fma (neg modifier)
      const float2v sv = __builtin_elementwise_fma(-accA[j], accA[j], accB[j]);
      const float sxy = sC[j] - mu_x * mu_y;
      const float num = (2.f * mu_x * mu_y + C1) * (2.f * sxy + C2);
      const float den = (mu_x * mu_x + mu_y * mu_y + C1) *
                        (fmaf(sv.x, sv.x, fmaf(sv.y, sv.y, C2)));
      lsum = fmaf(num, __builtin_amdgcn_rcpf(den), lsum);
    }
  }

  // ---- Block reduction -> partial[bid] ----
#pragma unroll
  for (int off = 32; off > 0; off >>= 1) lsum += __shfl_xor(lsum, off, 64);
  if ((tid & 63) == 0) wsums[tid >> 6] = lsum;
  __syncthreads();
  if (tid == 0)
    partial[bid] = (wsums[0] + wsums[1]) + (wsums[2] + wsums[3]);
}

__global__ __launch_bounds__(1024) void ssim_reduce_kernel(
    const float* __restrict__ partial, float* __restrict__ out) {
  float s = 0.f;
  for (int i = threadIdx.x; i < NBLOCKS; i += 1024) s += partial[i];
#pragma unroll
  for (int off = 32; off > 0; off >>= 1) s += __shfl_xor(s, off, 64);
  __shared__ float ws[16];
  if ((threadIdx.x & 63) == 0) ws[threadIdx.x >> 6] = s;
  __syncthreads();
  if (threadIdx.x == 0) {
    float t = 0.f;
#pragma unroll
    for (int i = 0; i < 16; ++i) t += ws[i];
    out[0] = t * (1.0f / (float)TOTAL_ELEMS);
  }
}

extern "C" void kernel_launch(void* const* d_in, const int* in_sizes, int n_in,
                              void* d_out, int out_size, void* d_ws,
                              size_t ws_size, hipStream_t stream) {
  const float* pred = (const float*)d_in[0];
  const float* targ = (const float*)d_in[1];
  float* out = (float*)d_out;
  float* partial = (float*)d_ws;

  ssim_tile_kernel<<<NBLOCKS, NTHREADS, 0, stream>>>(pred, targ, partial);
  ssim_reduce_kernel<<<1, 1024, 0, stream>>>(partial, out);
}